// Round 5
// baseline (453.700 us; speedup 1.0000x reference)
//
#include <hip/hip_runtime.h>

#define Nn    8192
#define FIN   256
#define FOUTc 128
#define MAXN  512   // degree ~ Binom(8192,0.01): mean 82, row max ~125 << 512
#define RPB   4     // rows per k_agg block

typedef float f32x4 __attribute__((ext_vector_type(4)));

// ---- Stage 1: x' = x@W + bias (materialized, 4 MB -> L2-resident), fused with
//      s_src = x'·phi_src, s_dst = x'·phi_dst. One wave per 8 rows. ----
__global__ __launch_bounds__(256) void k_xp(const float* __restrict__ x,
                                            const float* __restrict__ w,
                                            const float* __restrict__ bias,
                                            const float* __restrict__ phi,
                                            float* __restrict__ xp,
                                            float* __restrict__ s_src,
                                            float* __restrict__ s_dst)
{
    const int wave = blockIdx.x * 4 + (threadIdx.x >> 6);   // 256 blocks x 4 waves = 1024
    const int lane = threadIdx.x & 63;
    const int row0 = wave * 8;

    const float2 bv = ((const float2*)bias)[lane];
    const float2 ps = ((const float2*)phi)[lane];
    const float2 pd = ((const float2*)(phi + FOUTc))[lane];

    const float* xr = x + (size_t)row0 * FIN;
    float2 acc[8];
#pragma unroll
    for (int r = 0; r < 8; r++) acc[r] = make_float2(0.f, 0.f);

#pragma unroll 4
    for (int k = 0; k < FIN; k++) {
        const float2 wv = ((const float2*)(w + (size_t)k * FOUTc))[lane];
#pragma unroll
        for (int r = 0; r < 8; r++) {
            const float xv = xr[r * FIN + k];            // wave-uniform (scalar) load
            acc[r].x = fmaf(xv, wv.x, acc[r].x);
            acc[r].y = fmaf(xv, wv.y, acc[r].y);
        }
    }

#pragma unroll
    for (int r = 0; r < 8; r++) {
        const float2 h = make_float2(acc[r].x + bv.x, acc[r].y + bv.y);
        ((float2*)(xp + (size_t)(row0 + r) * FOUTc))[lane] = h;
        float a = h.x * ps.x + h.y * ps.y;
        float b = h.x * pd.x + h.y * pd.y;
#pragma unroll
        for (int off = 32; off > 0; off >>= 1) {
            a += __shfl_down(a, off, 64);
            b += __shfl_down(b, off, 64);
        }
        if (lane == 0) { s_src[row0 + r] = a; s_dst[row0 + r] = b; }
    }
}

// Producer helper: stream one adj row (nt, 4 chunks x 8 float4/lane) and compact
// nonzero columns (+ self-loop) into nbrb/cnt. Runs on ONE wave; its vmcnt waits
// are private to that wave, so consumer waves' gather latency is never chained
// behind these HBM loads.
__device__ __forceinline__ void compact_row(const float* __restrict__ adj, int row,
                                            int* __restrict__ nbrb, int* __restrict__ cnt,
                                            int lane)
{
    const f32x4* arow4 = (const f32x4*)(adj + (size_t)row * Nn);
#pragma unroll 1
    for (int c = 0; c < 4; c++) {
        f32x4 buf[8];
#pragma unroll
        for (int k = 0; k < 8; k++)
            buf[k] = __builtin_nontemporal_load(arow4 + c * 512 + k * 64 + lane);
#pragma unroll
        for (int k = 0; k < 8; k++) {
            const int j0 = (c * 512 + k * 64 + lane) * 4;
#pragma unroll
            for (int p = 0; p < 4; p++) {
                const int j = j0 + p;
                if (buf[k][p] != 0.f || j == row) {      // mask = adj + I > 0
                    const int pos = atomicAdd(cnt, 1);
                    if (pos < MAXN) nbrb[pos] = j;
                }
            }
        }
    }
}

// ---- Stage 2 (192 threads = 3 waves; wave 2 = producer, waves 0-1 = consumers).
//      Producer streams row t+1's adjacency into LDS double buffer while consumers
//      run softmax + gather + write for row t. One barrier per row.
//      RACE-FREE duplicated softmax: each consumer wave keeps pre-exp s_dst values
//      in REGISTERS (sdv[8], compile-time indexed); the only LDS writes are the
//      final e-values + padding, bit-identical across waves (same IEEE ops) ->
//      idempotent under any interleaving. Each wave writes all of wts[0..L) itself
//      before its own gather reads (in-wave RAW order), so neither wave depends on
//      the other's progress.
//      exp(NEG_INF - m) == 0 in fp32 => sparse softmax exact; lrelu monotone =>
//      m = lrelu(s_src[i] + max_j s_dst[j]); self-loop guarantees l >= 1.
//      bias folded into x' (softmax weights sum to 1). ----
__global__ __launch_bounds__(192) void k_agg(const float* __restrict__ adj,
                                             const float* __restrict__ xp,
                                             const float* __restrict__ s_src,
                                             const float* __restrict__ s_dst,
                                             float* __restrict__ out)
{
    __shared__ int   nbr[2][MAXN];
    __shared__ float wts[2][MAXN];
    __shared__ int   cnts[2];

    const int tid  = threadIdx.x;
    const int lane = tid & 63;
    const int row0 = blockIdx.x * RPB;

    if (tid == 0) { cnts[0] = 0; cnts[1] = 0; }
    __syncthreads();

    // Prologue: producer fills buffer 0 with row0's neighbor list.
    if (tid >= 128) compact_row(adj, row0, nbr[0], &cnts[0], lane);
    __syncthreads();

    for (int t = 0; t < RPB; t++) {
        const int cur = t & 1;
        const int row = row0 + t;

        if (tid >= 128) {
            // ---- producer: stage row t+1 into the other buffer ----
            if (t + 1 < RPB) {
                const int nxt = cur ^ 1;
                if (lane == 0) cnts[nxt] = 0;            // same-wave DS order precedes atomics
                compact_row(adj, row + 1, nbr[nxt], &cnts[nxt], lane);
            }
        } else {
            // ---- consumers: process row t from buffer cur ----
            const int Lr   = cnts[cur];
            const int L    = (Lr < MAXN) ? Lr : MAXN;
            const int Lpad = (L + 3) & ~3;
            const float ssi = s_src[row];

            // softmax, duplicated per consumer wave; pre-exp values live in registers.
            float sdv[8];
            float lmax = -1e30f;
#pragma unroll
            for (int q = 0; q < 8; q++) {
                const int n = lane + 64 * q;
                sdv[q] = -1e30f;
                if (n < L) {
                    sdv[q] = s_dst[nbr[cur][n]];
                    lmax = fmaxf(lmax, sdv[q]);
                }
            }
#pragma unroll
            for (int off = 32; off > 0; off >>= 1)
                lmax = fmaxf(lmax, __shfl_xor(lmax, off, 64));
            const float Sm  = ssi + lmax;
            const float m_i = (Sm >= 0.f) ? Sm : 0.2f * Sm;

            float lsum = 0.f;
#pragma unroll
            for (int q = 0; q < 8; q++) {
                const int n = lane + 64 * q;
                if (n < L) {
                    float S = ssi + sdv[q];
                    S = (S >= 0.f) ? S : 0.2f * S;
                    const float e = __expf(S - m_i);
                    wts[cur][n] = e;                     // idempotent duplicate write
                    lsum += e;
                }
            }
#pragma unroll
            for (int off = 32; off > 0; off >>= 1) lsum += __shfl_xor(lsum, off, 64);
            const float inv = 1.f / lsum;

            for (int n = L + lane; n < Lpad; n += 64) {  // pad to x4 (idempotent writes)
                nbr[cur][n] = row;
                wts[cur][n] = 0.f;
            }

            // gather: 1 thread per output feature, all neighbors, 4 chains.
            const int o = tid;                           // 0..127
            const float* xpo = xp + o;
            float h0 = 0.f, h1 = 0.f, h2 = 0.f, h3 = 0.f;
            for (int n = 0; n < Lpad; n += 4) {
                const int   j0 = nbr[cur][n],     j1 = nbr[cur][n + 1];
                const int   j2 = nbr[cur][n + 2], j3 = nbr[cur][n + 3];
                const float w0 = wts[cur][n],     w1 = wts[cur][n + 1];
                const float w2 = wts[cur][n + 2], w3 = wts[cur][n + 3];
                h0 = fmaf(w0, xpo[(size_t)j0 * FOUTc], h0);
                h1 = fmaf(w1, xpo[(size_t)j1 * FOUTc], h1);
                h2 = fmaf(w2, xpo[(size_t)j2 * FOUTc], h2);
                h3 = fmaf(w3, xpo[(size_t)j3 * FOUTc], h3);
            }
            out[(size_t)row * FOUTc + o] = ((h0 + h1) + (h2 + h3)) * inv;  // bias in x'
        }
        __syncthreads();   // swap double buffer
    }
}

extern "C" void kernel_launch(void* const* d_in, const int* in_sizes, int n_in,
                              void* d_out, int out_size, void* d_ws, size_t ws_size,
                              hipStream_t stream)
{
    (void)out_size; (void)ws_size;
    const float* adj  = (const float*)d_in[0];
    const float* x    = (const float*)d_in[1];
    const float* w    = (const float*)d_in[2];
    const float* bias = (const float*)d_in[3];
    const float* phi  = (const float*)d_in[4];
    for (int i = 0; i < n_in; i++) {
        switch (in_sizes[i]) {
            case Nn * Nn:     adj  = (const float*)d_in[i]; break;
            case Nn * FIN:    x    = (const float*)d_in[i]; break;
            case FIN * FOUTc: w    = (const float*)d_in[i]; break;
            case FOUTc:       bias = (const float*)d_in[i]; break;
            case 2 * FOUTc:   phi  = (const float*)d_in[i]; break;
        }
    }
    float* out = (float*)d_out;

    float* xp    = (float*)d_ws;             // 8192 x 128 = 4 MB
    float* s_src = xp + (size_t)Nn * FOUTc;  // 32 KB
    float* s_dst = s_src + Nn;               // 32 KB

    hipLaunchKernelGGL(k_xp,  dim3(256),    dim3(256), 0, stream,
                       x, w, bias, phi, xp, s_src, s_dst);
    hipLaunchKernelGGL(k_agg, dim3(Nn/RPB), dim3(192), 0, stream,
                       adj, xp, s_src, s_dst, out);
}

// Round 6
// 412.921 us; speedup vs baseline: 1.0988x; 1.0988x over previous
//
#include <hip/hip_runtime.h>

#define Nn     8192
#define FIN    256
#define FOUTc  128
#define MAXN   512   // CSR row stride; degree ~ Binom(8192,0.01): mean 82, max ~125
#define LCAP   504   // clamp so Lpad (x8) <= MAXN
#define NXPB   256   // xp blocks at the head of k1's grid

typedef float f32x4 __attribute__((ext_vector_type(4)));

// ---- k1: [blocks 0..255] x' = x@W + bias -> xp, s_src, s_dst (compute-bound,
//      hidden under the scan). [blocks 256..8447] stream one adj row (nt loads),
//      compact nonzero cols (+ self-loop) into CSR. Scan tail is ~300 cy, so the
//      adj HBM stream stays saturated. ----
__global__ __launch_bounds__(256) void k1(const float* __restrict__ adj,
                                          const float* __restrict__ x,
                                          const float* __restrict__ w,
                                          const float* __restrict__ bias,
                                          const float* __restrict__ phi,
                                          float* __restrict__ xp,
                                          float* __restrict__ s_src,
                                          float* __restrict__ s_dst,
                                          int* __restrict__ csr,
                                          int* __restrict__ csr_cnt)
{
    __shared__ int nbr[MAXN];
    __shared__ int cnt;
    const int tid = threadIdx.x;
    const int bid = blockIdx.x;

    if (bid < NXPB) {
        // ---- xp path: one wave per 8 rows (W row reused 8x from L2) ----
        const int wave = bid * 4 + (tid >> 6);           // 1024 waves x 8 rows = 8192
        const int lane = tid & 63;
        const int row0 = wave * 8;

        const float2 bv = ((const float2*)bias)[lane];
        const float2 ps = ((const float2*)phi)[lane];
        const float2 pd = ((const float2*)(phi + FOUTc))[lane];

        const float* xr = x + (size_t)row0 * FIN;
        float2 acc[8];
#pragma unroll
        for (int r = 0; r < 8; r++) acc[r] = make_float2(0.f, 0.f);

#pragma unroll 4
        for (int k = 0; k < FIN; k++) {
            const float2 wv = ((const float2*)(w + (size_t)k * FOUTc))[lane];
#pragma unroll
            for (int r = 0; r < 8; r++) {
                const float xv = xr[r * FIN + k];        // wave-uniform load
                acc[r].x = fmaf(xv, wv.x, acc[r].x);
                acc[r].y = fmaf(xv, wv.y, acc[r].y);
            }
        }
#pragma unroll
        for (int r = 0; r < 8; r++) {
            const float2 h = make_float2(acc[r].x + bv.x, acc[r].y + bv.y);
            ((float2*)(xp + (size_t)(row0 + r) * FOUTc))[lane] = h;
            float a = h.x * ps.x + h.y * ps.y;
            float b = h.x * pd.x + h.y * pd.y;
#pragma unroll
            for (int off = 32; off > 0; off >>= 1) {
                a += __shfl_down(a, off, 64);
                b += __shfl_down(b, off, 64);
            }
            if (lane == 0) { s_src[row0 + r] = a; s_dst[row0 + r] = b; }
        }
        return;
    }

    // ---- scan path: row i = bid - NXPB ----
    const int i = bid - NXPB;
    if (tid == 0) cnt = 0;
    __syncthreads();

    const f32x4* arow4 = (const f32x4*)(adj + (size_t)i * Nn);
    f32x4 buf[8];
#pragma unroll
    for (int t = 0; t < 8; t++) buf[t] = __builtin_nontemporal_load(arow4 + t * 256 + tid);

#pragma unroll
    for (int t = 0; t < 8; t++) {
        const int j0 = (t * 256 + tid) * 4;
#pragma unroll
        for (int p = 0; p < 4; p++) {
            const int j = j0 + p;
            if (buf[t][p] != 0.f || j == i) {            // mask = adj + I > 0
                const int pos = atomicAdd(&cnt, 1);
                if (pos < LCAP) nbr[pos] = j;
            }
        }
    }
    __syncthreads();
    const int L    = (cnt < LCAP) ? cnt : LCAP;
    const int Lpad = (L + 7) & ~7;
    if (tid < Lpad - L) nbr[L + tid] = i;                // pad with self (w=0 in k2)
    __syncthreads();

    int* crow = csr + (size_t)i * MAXN;
    for (int n = tid; n < Lpad; n += 256) crow[n] = nbr[n];
    if (tid == 0) csr_cnt[i] = L;
}

// ---- k2: softmax + gather, zero HBM dependency (CSR ~20MB + xp 4MB, L2-resident).
//      exp(NEG_INF - m) == 0 in fp32 => sparse softmax exact; lrelu monotone =>
//      m = lrelu(s_src[i] + max_j s_dst[j]); self-loop guarantees l >= 1.
//      bias folded into x' (softmax weights sum to 1). ----
__global__ __launch_bounds__(256) void k2(const int* __restrict__ csr,
                                          const int* __restrict__ csr_cnt,
                                          const float* __restrict__ xp,
                                          const float* __restrict__ s_src,
                                          const float* __restrict__ s_dst,
                                          float* __restrict__ out)
{
    __shared__ int   nbrs[MAXN];
    __shared__ float wts[MAXN];
    __shared__ float hp[2][FOUTc];
    __shared__ float red_m[4];
    __shared__ float red_s[4];

    const int tid = threadIdx.x;
    const int i = blockIdx.x;
    const int L = csr_cnt[i];
    const int Lpad = (L + 7) & ~7;
    const int* crow = csr + (size_t)i * MAXN;
    const float ssi = s_src[i];

    // Phase 1: stage indices to LDS, gather s_dst, block max.
    float lmax = -1e30f;
    for (int n = tid; n < Lpad; n += 256) {
        const int j = crow[n];
        nbrs[n] = j;
        if (n < L) {
            const float sd = s_dst[j];
            wts[n] = sd;
            lmax = fmaxf(lmax, sd);
        } else {
            wts[n] = 0.f;                                // pad: weight 0 (pre-set)
        }
    }
#pragma unroll
    for (int off = 32; off > 0; off >>= 1)
        lmax = fmaxf(lmax, __shfl_xor(lmax, off, 64));
    if ((tid & 63) == 0) red_m[tid >> 6] = lmax;
    __syncthreads();
    const float maxd = fmaxf(fmaxf(red_m[0], red_m[1]), fmaxf(red_m[2], red_m[3]));
    const float Sm   = ssi + maxd;
    const float m_i  = (Sm >= 0.f) ? Sm : 0.2f * Sm;

    // Phase 2: exp weights + denominator.
    float lsum = 0.f;
    for (int n = tid; n < L; n += 256) {
        float S = ssi + wts[n];
        S = (S >= 0.f) ? S : 0.2f * S;
        const float e = __expf(S - m_i);
        wts[n] = e;
        lsum += e;
    }
#pragma unroll
    for (int off = 32; off > 0; off >>= 1) lsum += __shfl_xor(lsum, off, 64);
    if ((tid & 63) == 0) red_s[tid >> 6] = lsum;
    __syncthreads();                                     // publishes wts[] + red_s
    const float l_i = (red_s[0] + red_s[1]) + (red_s[2] + red_s[3]);
    const float inv = 1.f / l_i;

    // Phase 3: h[o] = sum_n w_n * x'[j_n][o]; 2 groups x 4 chains; per-neighbor
    // 512B coalesced from L2 (xp = 4MB).
    const int o  = tid & 127;
    const int g  = tid >> 7;
    const int Lh = Lpad >> 1;                            // multiple of 4
    const int base = g * Lh;
    const float* xpo = xp + o;
    float h0 = 0.f, h1 = 0.f, h2 = 0.f, h3 = 0.f;
    for (int n = base; n < base + Lh; n += 4) {
        const int   j0 = nbrs[n],   j1 = nbrs[n+1], j2 = nbrs[n+2], j3 = nbrs[n+3];
        const float w0 = wts[n],    w1 = wts[n+1],  w2 = wts[n+2],  w3 = wts[n+3];
        h0 = fmaf(w0, xpo[(size_t)j0 * FOUTc], h0);
        h1 = fmaf(w1, xpo[(size_t)j1 * FOUTc], h1);
        h2 = fmaf(w2, xpo[(size_t)j2 * FOUTc], h2);
        h3 = fmaf(w3, xpo[(size_t)j3 * FOUTc], h3);
    }
    hp[g][o] = (h0 + h1) + (h2 + h3);
    __syncthreads();
    if (tid < FOUTc)
        out[(size_t)i * FOUTc + tid] = (hp[0][tid] + hp[1][tid]) * inv;   // bias in x'
}

extern "C" void kernel_launch(void* const* d_in, const int* in_sizes, int n_in,
                              void* d_out, int out_size, void* d_ws, size_t ws_size,
                              hipStream_t stream)
{
    (void)out_size; (void)ws_size;
    const float* adj  = (const float*)d_in[0];
    const float* x    = (const float*)d_in[1];
    const float* w    = (const float*)d_in[2];
    const float* bias = (const float*)d_in[3];
    const float* phi  = (const float*)d_in[4];
    for (int i = 0; i < n_in; i++) {
        switch (in_sizes[i]) {
            case Nn * Nn:     adj  = (const float*)d_in[i]; break;
            case Nn * FIN:    x    = (const float*)d_in[i]; break;
            case FIN * FOUTc: w    = (const float*)d_in[i]; break;
            case FOUTc:       bias = (const float*)d_in[i]; break;
            case 2 * FOUTc:   phi  = (const float*)d_in[i]; break;
        }
    }
    float* out = (float*)d_out;

    float* xp      = (float*)d_ws;                 // 8192 x 128 f32 = 4 MB
    float* s_src   = xp + (size_t)Nn * FOUTc;      // 32 KB
    float* s_dst   = s_src + Nn;                   // 32 KB
    int*   csr_cnt = (int*)(s_dst + Nn);           // 32 KB
    int*   csr     = csr_cnt + Nn;                 // 8192 x 512 i32 = 16 MB

    hipLaunchKernelGGL(k1, dim3(NXPB + Nn), dim3(256), 0, stream,
                       adj, x, w, bias, phi, xp, s_src, s_dst, csr, csr_cnt);
    hipLaunchKernelGGL(k2, dim3(Nn),        dim3(256), 0, stream,
                       csr, csr_cnt, xp, s_src, s_dst, out);
}